// Round 1
// 249.910 us; speedup vs baseline: 1.0476x; 1.0476x over previous
//
#include <hip/hip_runtime.h>
#include <cstddef>

// ---------------- problem constants ----------------
#define BB   8
#define CC   2
#define FF   256
#define TT   4160      // ncoefs
#define SS   64        // nb_slices
#define NW   128       // NWIN
#define KW   256       // 2*NWIN
#define EPSV 1e-5f

typedef __attribute__((ext_vector_type(8))) short bf16x8;   // 8 bf16 = 4 VGPRs
typedef __attribute__((ext_vector_type(4))) float f32x4;

// ---------------- ws layout (float offsets) ----------------
// y  : bf16 [4096][64][128] = 33,554,432 ushort = 16,777,216 floats (64 MiB)
// z  : bf16 concat buckets  = 17,301,504 ushort =  8,650,752 floats
// w1 : bf16 frag-ordered W_deo = 32,768 ushort  = 16,384 floats
// w2 : bf16 frag-ordered W_di  = 36,864 ushort  = 18,432 floats
#define YOFF    0
#define ZOFF    16777216
#define W1OFF   25427968
#define W2OFF   25444352
#define STATF   25462784
#define OFF_DA     256
#define OFF_DB     384
#define OFF_DIAB   544
#define OFF_STATR  1024    // 64 reps x [sum(128) | sq(128)]  (stage-1)
#define OFF_STATR2 17408   // 64 reps x [sum(16)  | sq(16) ]  (stage-2)
#define NZERO   19456

// manual bf16 conversions (RNE)
__device__ __forceinline__ unsigned short f2bf(float f) {
    unsigned int u = __builtin_bit_cast(unsigned int, f);
    u = (u + 0x7FFFu + ((u >> 16) & 1u)) >> 16;
    return (unsigned short)u;
}
__device__ __forceinline__ float bf2f(unsigned short h) {
    return __builtin_bit_cast(float, (unsigned int)h << 16);
}

// ---------------- prep: zero stats + frag-ordered bf16 W_deo (w1) + W_di (w2) ----------------
// w1: [ks(8)][nt(8)][lane(64)][j(8)]  = Wdeo[(nt*16+(lane&15))*256 + ks*32 + (lane>>4)*8 + j]
// w2 per bucket (Tk=MT/16): [ks(4)][t(Tk)][lane(64)][j(8)]
//                           = Wdi[(t*16+(lane&15))*128 + ks*32 + (lane>>4)*8 + j]
__global__ __launch_bounds__(256) void k_prep(
    const float* __restrict__ Wdeo,
    const float* __restrict__ Wdi0, const float* __restrict__ Wdi1,
    const float* __restrict__ Wdi2, const float* __restrict__ Wdi3,
    const float* __restrict__ Wdi4,
    unsigned short* __restrict__ w1, unsigned short* __restrict__ w2,
    float* __restrict__ statz)
{
    int gid = blockIdx.x * 256 + threadIdx.x;
    if (gid < NZERO) statz[gid] = 0.f;
    int id = gid - NZERO;
    if (id >= 0 && id < 32768) {
        int j = id & 7, lane = (id >> 3) & 63, nt = (id >> 9) & 7, ks = id >> 12;
        int n = nt * 16 + (lane & 15);
        int k = ks * 32 + ((lane >> 4) << 3) + j;
        w1[id] = f2bf(Wdeo[n * KW + k]);
    }
    id -= 32768;
    if (id >= 0 && id < 36864) {
        const float* W; int base, Tk;
        if (id < 2048)       { W = Wdi0; base = 0;     Tk = 1; }
        else if (id < 6144)  { W = Wdi1; base = 2048;  Tk = 2; }
        else if (id < 12288) { W = Wdi2; base = 6144;  Tk = 3; }
        else if (id < 20480) { W = Wdi3; base = 12288; Tk = 4; }
        else                 { W = Wdi4; base = 20480; Tk = 8; }
        int e = id - base;
        int j = e & 7, lane = (e >> 3) & 63, rest = e >> 9;
        int t = rest % Tk, ks = rest / Tk;
        int n = t * 16 + (lane & 15);
        int k = ks * 32 + ((lane >> 4) << 3) + j;
        w2[id] = f2bf(W[n * NW + k]);
    }
}

// ---------------- stage 1: normalize + deoverlap MFMA + stats (1 row / block) ----------------
__global__ __launch_bounds__(256) void k_deoverlap(
    const float* __restrict__ x, const float* __restrict__ imean,
    const float* __restrict__ iscale, const unsigned short* __restrict__ w1,
    unsigned short* __restrict__ y, float* __restrict__ statR)
{
    __shared__ __align__(16) unsigned short xs[4288];
    __shared__ float psA[4][64], pqA[4][64];
    const int tid = threadIdx.x;
    const int r   = blockIdx.x;
    const int c   = (r >> 8) & 1;

    {
        const float mval = imean[r & 255], sval = iscale[r & 255];
        const float* xr = x + (size_t)r * TT;
        for (int p2 = tid; p2 < 2144; p2 += 256) {
            int i = p2 * 2;
            int t = i - 64;
            float v0 = 0.f, v1 = 0.f;
            if (t >= 0 && t + 1 < TT) {
                float2 xv = *(const float2*)&xr[t];
                v0 = (xv.x + mval) * sval;
                v1 = (xv.y + mval) * sval;
            }
            int phys = i ^ (((i >> 6) & 7) << 3);
            unsigned int pk = (unsigned int)f2bf(v0) | ((unsigned int)f2bf(v1) << 16);
            *(unsigned int*)&xs[phys] = pk;
        }
    }
    __syncthreads();

    const int lane = tid & 63, wv = tid >> 6;
    const int q = lane >> 4, m = lane & 15;

    f32x4 acc[4][2] = {};   // [stile][ntile]
    for (int ks = 0; ks < 8; ++ks) {
        const int k0 = ks * 32;
        bf16x8 B0 = *(const bf16x8*)(w1 + ((size_t)((ks * 8 + 2 * wv + 0) * 64 + lane) << 3));
        bf16x8 B1 = *(const bf16x8*)(w1 + ((size_t)((ks * 8 + 2 * wv + 1) * 64 + lane) << 3));
#pragma unroll
        for (int st = 0; st < 4; ++st) {
            int idx  = (st * 16 + m) * 64 + k0 + q * 8;
            int phys = idx ^ (((idx >> 6) & 7) << 3);
            bf16x8 A = *(const bf16x8*)&xs[phys];
            acc[st][0] = __builtin_amdgcn_mfma_f32_16x16x32_bf16(A, B0, acc[st][0], 0, 0, 0);
            acc[st][1] = __builtin_amdgcn_mfma_f32_16x16x32_bf16(A, B1, acc[st][1], 0, 0, 0);
        }
    }

    // direct y store (bf16): col n = (2wv+t)*16+m, row s = st*16+q*4+reg
#pragma unroll
    for (int st = 0; st < 4; ++st)
#pragma unroll
        for (int t = 0; t < 2; ++t) {
            int n = (2 * wv + t) * 16 + m;
#pragma unroll
            for (int reg = 0; reg < 4; ++reg) {
                int s = st * 16 + q * 4 + reg;
                y[(size_t)r * 8192 + s * NW + n] = f2bf(acc[st][t][reg]);
            }
        }

    // per-(c,s) stats -> shfl16 -> LDS combine -> replicated atomics
#pragma unroll
    for (int st = 0; st < 4; ++st)
#pragma unroll
        for (int reg = 0; reg < 4; ++reg) {
            float ps = 0.f, pq = 0.f;
#pragma unroll
            for (int t = 0; t < 2; ++t) {
                float v = acc[st][t][reg];
                ps += v; pq += v * v;
            }
#pragma unroll
            for (int off = 8; off > 0; off >>= 1) {
                ps += __shfl_down(ps, off, 16);
                pq += __shfl_down(pq, off, 16);
            }
            if (m == 0) {
                int s = st * 16 + q * 4 + reg;
                psA[wv][s] = ps;
                pqA[wv][s] = pq;
            }
        }
    __syncthreads();
    if (tid < 128) {
        int s = tid & 63, which = tid >> 6;
        float v = which ? (pqA[0][s] + pqA[1][s] + pqA[2][s] + pqA[3][s])
                        : (psA[0][s] + psA[1][s] + psA[2][s] + psA[3][s]);
        int rep = blockIdx.x & 63;
        atomicAdd(&statR[rep * 256 + which * 128 + c * SS + s], v);
    }
}

// ---------------- stage 1b: fold replicas -> per-(c,s) BN coefficients ----------------
__global__ void k_deo_ab(const float* __restrict__ statR,
                         const float* __restrict__ g, const float* __restrict__ be,
                         float* __restrict__ da, float* __restrict__ db)
{
    int i = threadIdx.x;
    if (i < CC * SS) {
        float sm = 0.f, sq = 0.f;
        for (int rep = 0; rep < 64; ++rep) {
            sm += statR[rep * 256 + i];
            sq += statR[rep * 256 + 128 + i];
        }
        int c = i >> 6;
        const float N = (float)(BB * FF * NW);
        float mean = sm / N;
        float var  = sq / N - mean * mean;
        float a = g[c] * rsqrtf(var + EPSV);
        da[i] = a;
        db[i] = be[c] - mean * a;
    }
}

// ---------------- stage 2 body: fused BN+ReLU + GEMM for one bucket sub-block ----------------
// y read exactly once; BN applied once per y element; stats fused (replicated).
template <int Tk, int G>
__device__ __forceinline__ void deinterp_body(
    int sub,
    const unsigned short* __restrict__ y, const unsigned short* __restrict__ wb,
    const float* __restrict__ da, const float* __restrict__ db,
    unsigned short* __restrict__ zz, float* __restrict__ statR2,
    int p, int freqs, int kidx, float* ssum, float* ssq)
{
    constexpr int MT = Tk * 16;
    const int tid = threadIdx.x, lane = tid & 63, wv = tid >> 6;
    const int q = lane >> 4, m = lane & 15;
    const int bc = sub & 15;
    const int fg = sub >> 4;
    const int c  = bc & 1;
    const int s  = wv * 16 + m;
    const float aS = da[c * SS + s], bS = db[c * SS + s];

    f32x4 acc[G][Tk] = {};
    const unsigned short* ybase = y + ((size_t)(bc * FF + p + fg * G) * SS) * NW;

#pragma unroll
    for (int ks = 0; ks < 4; ++ks) {
        bf16x8 B[Tk];
#pragma unroll
        for (int t = 0; t < Tk; ++t)
            B[t] = *(const bf16x8*)(wb + ((size_t)((ks * Tk + t) * 64 + lane) << 3));
#pragma unroll
        for (int g = 0; g < G; ++g) {
            bf16x8 ar = *(const bf16x8*)(ybase + ((size_t)g * SS + s) * NW + ks * 32 + q * 8);
            bf16x8 af;
#pragma unroll
            for (int j = 0; j < 8; ++j) {
                float f = bf2f((unsigned short)ar[j]);
                f = fmaxf(fmaf(f, aS, bS), 0.f);
                af[j] = (short)f2bf(f);
            }
#pragma unroll
            for (int t = 0; t < Tk; ++t)
                acc[g][t] = __builtin_amdgcn_mfma_f32_16x16x32_bf16(af, B[t], acc[g][t], 0, 0, 0);
        }
    }

    float ls = 0.f, lq = 0.f;
#pragma unroll
    for (int g = 0; g < G; ++g) {
        size_t zrow = (size_t)(bc * freqs + fg * G + g) * SS;
#pragma unroll
        for (int t = 0; t < Tk; ++t)
#pragma unroll
            for (int reg = 0; reg < 4; ++reg) {
                float v = acc[g][t][reg];
                ls += v; lq += v * v;
                int srow = wv * 16 + q * 4 + reg;
                zz[(zrow + srow) * MT + t * 16 + m] = f2bf(v);
            }
    }
#pragma unroll
    for (int o = 32; o > 0; o >>= 1) {
        ls += __shfl_down(ls, o, 64);
        lq += __shfl_down(lq, o, 64);
    }
    if (lane == 0) { ssum[wv] = ls; ssq[wv] = lq; }
    __syncthreads();
    if (tid == 0) {
        int rep = sub & 63;
        atomicAdd(&statR2[rep * 32 + kidx * 2 + c],      ssum[0] + ssum[1] + ssum[2] + ssum[3]);
        atomicAdd(&statR2[rep * 32 + 16 + kidx * 2 + c], ssq[0] + ssq[1] + ssq[2] + ssq[3]);
    }
}

// ---------------- stage 2 fused: all 5 buckets in one launch ----------------
// Block ranges ordered heavy-first (buckets 3, 2, 4, then 1, 0) so the grid
// tail is made of the cheapest blocks.
//   [   0, 256) -> bucket3 Tk=4 G=4  (256 blocks)
//   [ 256, 512) -> bucket2 Tk=3 G=4  (256 blocks)
//   [ 512,1024) -> bucket4 Tk=8 G=2  (512 blocks)
//   [1024,1152) -> bucket1 Tk=2 G=4  (128 blocks)
//   [1152,1280) -> bucket0 Tk=1 G=4  (128 blocks)
__global__ __launch_bounds__(256) void k_deinterp_all(
    const unsigned short* __restrict__ y, const unsigned short* __restrict__ w2,
    const float* __restrict__ da, const float* __restrict__ db,
    unsigned short* __restrict__ z, float* __restrict__ statR2)
{
    __shared__ float ssum[4], ssq[4];
    const int b = blockIdx.x;
    if (b < 256) {
        deinterp_body<4, 4>(b,        y, w2 + 12288, da, db, z + 4718592, statR2, 128, 64, 3, ssum, ssq);
    } else if (b < 512) {
        deinterp_body<3, 4>(b - 256,  y, w2 + 6144,  da, db, z + 1572864, statR2,  64, 64, 2, ssum, ssq);
    } else if (b < 1024) {
        deinterp_body<8, 2>(b - 512,  y, w2 + 20480, da, db, z + 8912896, statR2, 192, 64, 4, ssum, ssq);
    } else if (b < 1152) {
        deinterp_body<2, 4>(b - 1024, y, w2 + 2048,  da, db, z + 524288,  statR2,  32, 32, 1, ssum, ssq);
    } else {
        deinterp_body<1, 4>(b - 1152, y, w2 + 0,     da, db, z + 0,       statR2,   0, 32, 0, ssum, ssq);
    }
}

// ---------------- stage 2b: fold replicas -> per-(bucket,c) BN coefficients ----------------
__global__ void k_di_ab(const float* __restrict__ statR2,
                        const float* __restrict__ g0, const float* __restrict__ g1,
                        const float* __restrict__ g2, const float* __restrict__ g3,
                        const float* __restrict__ g4,
                        const float* __restrict__ b0, const float* __restrict__ b1,
                        const float* __restrict__ b2, const float* __restrict__ b3,
                        const float* __restrict__ b4,
                        float* __restrict__ ab)
{
    int i = threadIdx.x;
    if (i < 10) {
        float sm = 0.f, sq = 0.f;
        for (int rep = 0; rep < 64; ++rep) {
            sm += statR2[rep * 32 + i];
            sq += statR2[rep * 32 + 16 + i];
        }
        int kb = i >> 1, c = i & 1;
        const float Nv[5] = {262144.f, 524288.f, 1572864.f, 2097152.f, 4194304.f};
        const float* gp[5] = {g0, g1, g2, g3, g4};
        const float* bp[5] = {b0, b1, b2, b3, b4};
        float mean = sm / Nv[kb];
        float var  = sq / Nv[kb] - mean * mean;
        float a = gp[kb][c] * rsqrtf(var + EPSV);
        ab[i * 2]     = a;
        ab[i * 2 + 1] = bp[kb][c] - mean * a;
    }
}

// ---------------- BN+ReLU epilogue: bf16 z -> fp32 out ----------------
__global__ __launch_bounds__(256) void k_bn_out(
    const unsigned short* __restrict__ z, const float* __restrict__ ab,
    float* __restrict__ out)
{
    int i4 = blockIdx.x * 256 + threadIdx.x;
    if (i4 >= 4325376) return;
    int kb, off4, cs4;
    if (i4 < 131072)       { kb = 0; off4 = 0;       cs4 = 8192;   }
    else if (i4 < 393216)  { kb = 1; off4 = 131072;  cs4 = 16384;  }
    else if (i4 < 1179648) { kb = 2; off4 = 393216;  cs4 = 49152;  }
    else if (i4 < 2228224) { kb = 3; off4 = 1179648; cs4 = 65536;  }
    else                   { kb = 4; off4 = 2228224; cs4 = 131072; }
    int c = ((i4 - off4) / cs4) & 1;
    float a = ab[(kb * 2 + c) * 2], b = ab[(kb * 2 + c) * 2 + 1];
    ushort4 u = *(const ushort4*)(z + (size_t)i4 * 4);
    float4 o;
    o.x = fmaxf(fmaf(bf2f(u.x), a, b), 0.f);
    o.y = fmaxf(fmaf(bf2f(u.y), a, b), 0.f);
    o.z = fmaxf(fmaf(bf2f(u.z), a, b), 0.f);
    o.w = fmaxf(fmaf(bf2f(u.w), a, b), 0.f);
    *(float4*)(out + (size_t)i4 * 4) = o;
}

// ---------------- launch ----------------
extern "C" void kernel_launch(void* const* d_in, const int* in_sizes, int n_in,
                              void* d_out, int out_size, void* d_ws, size_t ws_size,
                              hipStream_t stream)
{
    const float* x      = (const float*)d_in[0];
    const float* imean  = (const float*)d_in[1];
    const float* iscale = (const float*)d_in[2];
    const float* Wdeo   = (const float*)d_in[3];
    const float* gdeo   = (const float*)d_in[4];
    const float* bdeo   = (const float*)d_in[5];
    const float* Wdi[5] = {(const float*)d_in[7],  (const float*)d_in[10],
                           (const float*)d_in[13], (const float*)d_in[16],
                           (const float*)d_in[19]};
    const float* gdi[5] = {(const float*)d_in[8],  (const float*)d_in[11],
                           (const float*)d_in[14], (const float*)d_in[17],
                           (const float*)d_in[20]};
    const float* bdi[5] = {(const float*)d_in[9],  (const float*)d_in[12],
                           (const float*)d_in[15], (const float*)d_in[18],
                           (const float*)d_in[21]};
    float* out = (float*)d_out;
    float* ws  = (float*)d_ws;

    unsigned short* y  = (unsigned short*)(ws + YOFF);
    unsigned short* z  = (unsigned short*)(ws + ZOFF);
    unsigned short* w1 = (unsigned short*)(ws + W1OFF);
    unsigned short* w2 = (unsigned short*)(ws + W2OFF);
    float* st     = ws + STATF;
    float* da     = st + OFF_DA;
    float* db     = st + OFF_DB;
    float* diab   = st + OFF_DIAB;
    float* statR  = st + OFF_STATR;
    float* statR2 = st + OFF_STATR2;

    k_prep<<<348, 256, 0, stream>>>(Wdeo, Wdi[0], Wdi[1], Wdi[2], Wdi[3], Wdi[4],
                                    w1, w2, st);

    k_deoverlap<<<BB * CC * FF, 256, 0, stream>>>(x, imean, iscale, w1, y, statR);
    k_deo_ab<<<1, 128, 0, stream>>>(statR, gdeo, bdeo, da, db);

    k_deinterp_all<<<1280, 256, 0, stream>>>(y, w2, da, db, z, statR2);

    k_di_ab<<<1, 16, 0, stream>>>(statR2,
                                  gdi[0], gdi[1], gdi[2], gdi[3], gdi[4],
                                  bdi[0], bdi[1], bdi[2], bdi[3], bdi[4], diab);

    k_bn_out<<<16896, 256, 0, stream>>>(z, diab, out);
}

// Round 2
// 242.402 us; speedup vs baseline: 1.0800x; 1.0310x over previous
//
#include <hip/hip_runtime.h>
#include <cstddef>

// ---------------- problem constants ----------------
#define BB   8
#define CC   2
#define FF   256
#define TT   4160      // ncoefs
#define SS   64        // nb_slices
#define NW   128       // NWIN
#define KW   256       // 2*NWIN
#define EPSV 1e-5f

typedef __attribute__((ext_vector_type(8))) short bf16x8;   // 8 bf16 = 4 VGPRs
typedef __attribute__((ext_vector_type(4))) float f32x4;

// ---------------- ws layout (float offsets) ----------------
#define YOFF    0
#define ZOFF    16777216
#define W1OFF   25427968
#define W2OFF   25444352
#define STATF   25462784
#define OFF_DA     256
#define OFF_DB     384
#define OFF_DIAB   544
#define OFF_STATR  1024    // 64 reps x [sum(128) | sq(128)]  (stage-1)
#define OFF_STATR2 17408   // 64 reps x [sum(16)  | sq(16) ]  (stage-2)
#define NZERO   19456

// manual bf16 conversions (RNE)
__device__ __forceinline__ unsigned short f2bf(float f) {
    unsigned int u = __builtin_bit_cast(unsigned int, f);
    u = (u + 0x7FFFu + ((u >> 16) & 1u)) >> 16;
    return (unsigned short)u;
}
__device__ __forceinline__ float bf2f(unsigned short h) {
    return __builtin_bit_cast(float, (unsigned int)h << 16);
}

// ---------------- prep: zero stats + frag-ordered bf16 W_deo (w1) + W_di (w2) ----------------
__global__ __launch_bounds__(256) void k_prep(
    const float* __restrict__ Wdeo,
    const float* __restrict__ Wdi0, const float* __restrict__ Wdi1,
    const float* __restrict__ Wdi2, const float* __restrict__ Wdi3,
    const float* __restrict__ Wdi4,
    unsigned short* __restrict__ w1, unsigned short* __restrict__ w2,
    float* __restrict__ statz)
{
    int gid = blockIdx.x * 256 + threadIdx.x;
    if (gid < NZERO) statz[gid] = 0.f;
    int id = gid - NZERO;
    if (id >= 0 && id < 32768) {
        int j = id & 7, lane = (id >> 3) & 63, nt = (id >> 9) & 7, ks = id >> 12;
        int n = nt * 16 + (lane & 15);
        int k = ks * 32 + ((lane >> 4) << 3) + j;
        w1[id] = f2bf(Wdeo[n * KW + k]);
    }
    id -= 32768;
    if (id >= 0 && id < 36864) {
        const float* W; int base, Tk;
        if (id < 2048)       { W = Wdi0; base = 0;     Tk = 1; }
        else if (id < 6144)  { W = Wdi1; base = 2048;  Tk = 2; }
        else if (id < 12288) { W = Wdi2; base = 6144;  Tk = 3; }
        else if (id < 20480) { W = Wdi3; base = 12288; Tk = 4; }
        else                 { W = Wdi4; base = 20480; Tk = 8; }
        int e = id - base;
        int j = e & 7, lane = (e >> 3) & 63, rest = e >> 9;
        int t = rest % Tk, ks = rest / Tk;
        int n = t * 16 + (lane & 15);
        int k = ks * 32 + ((lane >> 4) << 3) + j;
        w2[id] = f2bf(W[n * NW + k]);
    }
}

// ---------------- stage 1: normalize + deoverlap MFMA + stats (1 row / block) ----------------
// MFMA operand-swapped: acc = mfma(W_frag, X_frag) so the register dim of the
// output maps to n (contiguous in y) -> 8-byte vector stores + cheap stats.
__global__ __launch_bounds__(256) void k_deoverlap(
    const float* __restrict__ x, const float* __restrict__ imean,
    const float* __restrict__ iscale, const unsigned short* __restrict__ w1,
    unsigned short* __restrict__ y, float* __restrict__ statR)
{
    __shared__ __align__(16) unsigned short xs[4288];
    __shared__ float psA[4][64], pqA[4][64];
    const int tid = threadIdx.x;
    const int r   = blockIdx.x;
    const int c   = (r >> 8) & 1;

    {
        const float mval = imean[r & 255], sval = iscale[r & 255];
        const float* xr = x + (size_t)r * TT;
        for (int p2 = tid; p2 < 2144; p2 += 256) {
            int i = p2 * 2;
            int t = i - 64;
            float v0 = 0.f, v1 = 0.f;
            if (t >= 0 && t + 1 < TT) {
                float2 xv = *(const float2*)&xr[t];
                v0 = (xv.x + mval) * sval;
                v1 = (xv.y + mval) * sval;
            }
            int phys = i ^ (((i >> 6) & 7) << 3);
            unsigned int pk = (unsigned int)f2bf(v0) | ((unsigned int)f2bf(v1) << 16);
            *(unsigned int*)&xs[phys] = pk;
        }
    }
    __syncthreads();

    const int lane = tid & 63, wv = tid >> 6;
    const int q = lane >> 4, m = lane & 15;

    f32x4 acc[4][2] = {};   // [stile][ntile]; D rows = n (reg dim), cols = s (m)
    // double-buffered w1 fragment loads: pull global loads off the MFMA chain
    bf16x8 Bc0 = *(const bf16x8*)(w1 + ((size_t)((0 * 8 + 2 * wv + 0) * 64 + lane) << 3));
    bf16x8 Bc1 = *(const bf16x8*)(w1 + ((size_t)((0 * 8 + 2 * wv + 1) * 64 + lane) << 3));
#pragma unroll
    for (int ks = 0; ks < 8; ++ks) {
        bf16x8 Bn0, Bn1;
        if (ks < 7) {
            Bn0 = *(const bf16x8*)(w1 + ((size_t)(((ks + 1) * 8 + 2 * wv + 0) * 64 + lane) << 3));
            Bn1 = *(const bf16x8*)(w1 + ((size_t)(((ks + 1) * 8 + 2 * wv + 1) * 64 + lane) << 3));
        }
        const int k0 = ks * 32;
#pragma unroll
        for (int st = 0; st < 4; ++st) {
            int idx  = (st * 16 + m) * 64 + k0 + q * 8;
            int phys = idx ^ (((idx >> 6) & 7) << 3);
            bf16x8 A = *(const bf16x8*)&xs[phys];
            acc[st][0] = __builtin_amdgcn_mfma_f32_16x16x32_bf16(Bc0, A, acc[st][0], 0, 0, 0);
            acc[st][1] = __builtin_amdgcn_mfma_f32_16x16x32_bf16(Bc1, A, acc[st][1], 0, 0, 0);
        }
        Bc0 = Bn0; Bc1 = Bn1;
    }

    // y store: row s = st*16+m, cols n = (2wv+t)*16 + q*4 + reg -> one ushort4 store
    // stats: per thread s is fixed per st -> reduce over q-groups with 2 shfl_xor
#pragma unroll
    for (int st = 0; st < 4; ++st) {
        float ps = 0.f, pq = 0.f;
#pragma unroll
        for (int t = 0; t < 2; ++t) {
            ushort4 u;
            u.x = f2bf(acc[st][t][0]);
            u.y = f2bf(acc[st][t][1]);
            u.z = f2bf(acc[st][t][2]);
            u.w = f2bf(acc[st][t][3]);
            *(ushort4*)&y[(size_t)r * 8192 + (st * 16 + m) * NW + (2 * wv + t) * 16 + q * 4] = u;
#pragma unroll
            for (int reg = 0; reg < 4; ++reg) {
                float v = acc[st][t][reg];
                ps += v; pq += v * v;
            }
        }
        ps += __shfl_xor(ps, 16, 64);  pq += __shfl_xor(pq, 16, 64);
        ps += __shfl_xor(ps, 32, 64);  pq += __shfl_xor(pq, 32, 64);
        if (q == 0) { psA[wv][st * 16 + m] = ps; pqA[wv][st * 16 + m] = pq; }
    }
    __syncthreads();
    if (tid < 128) {
        int s = tid & 63, which = tid >> 6;
        float v = which ? (pqA[0][s] + pqA[1][s] + pqA[2][s] + pqA[3][s])
                        : (psA[0][s] + psA[1][s] + psA[2][s] + psA[3][s]);
        int rep = blockIdx.x & 63;
        atomicAdd(&statR[rep * 256 + which * 128 + c * SS + s], v);
    }
}

// ---------------- stage 1b: fold replicas -> per-(c,s) BN coefficients ----------------
__global__ void k_deo_ab(const float* __restrict__ statR,
                         const float* __restrict__ g, const float* __restrict__ be,
                         float* __restrict__ da, float* __restrict__ db)
{
    __shared__ float red[4][256];
    int tid = threadIdx.x;
    int i = tid & 127, h = tid >> 7;          // 512 threads: 4 rep-chunks
    float sm = 0.f, sq = 0.f;
    for (int rep = h; rep < 64; rep += 4) {
        sm += statR[rep * 256 + i];
        sq += statR[rep * 256 + 128 + i];
    }
    red[h][i] = sm; red[h][128 + i] = sq;
    __syncthreads();
    if (h == 0) {
        sm = red[0][i] + red[1][i] + red[2][i] + red[3][i];
        sq = red[0][128 + i] + red[1][128 + i] + red[2][128 + i] + red[3][128 + i];
        int c = i >> 6;
        const float N = (float)(BB * FF * NW);
        float mean = sm / N;
        float var  = sq / N - mean * mean;
        float a = g[c] * rsqrtf(var + EPSV);
        da[i] = a;
        db[i] = be[c] - mean * a;
    }
}

// ---------------- stage 2 body: fused BN+ReLU + GEMM for one bucket sub-block ----------------
// Operand-swapped MFMA: D rows = m-cols of z (reg dim, contiguous), cols = s.
template <int Tk, int G>
__device__ __forceinline__ void deinterp_body(
    int sub,
    const unsigned short* __restrict__ y, const unsigned short* __restrict__ wb,
    const float* __restrict__ da, const float* __restrict__ db,
    unsigned short* __restrict__ zz, float* __restrict__ statR2,
    int p, int freqs, int kidx, float* ssum, float* ssq)
{
    constexpr int MT = Tk * 16;
    const int tid = threadIdx.x, lane = tid & 63, wv = tid >> 6;
    const int q = lane >> 4, m = lane & 15;
    const int bc = sub & 15;
    const int fg = sub >> 4;
    const int c  = bc & 1;
    const int s  = wv * 16 + m;
    const float aS = da[c * SS + s], bS = db[c * SS + s];

    f32x4 acc[G][Tk] = {};
    const unsigned short* ybase = y + ((size_t)(bc * FF + p + fg * G) * SS) * NW;

#pragma unroll
    for (int ks = 0; ks < 4; ++ks) {
        bf16x8 B[Tk];
#pragma unroll
        for (int t = 0; t < Tk; ++t)
            B[t] = *(const bf16x8*)(wb + ((size_t)((ks * Tk + t) * 64 + lane) << 3));
#pragma unroll
        for (int g = 0; g < G; ++g) {
            bf16x8 ar = *(const bf16x8*)(ybase + ((size_t)g * SS + s) * NW + ks * 32 + q * 8);
            bf16x8 af;
#pragma unroll
            for (int j = 0; j < 8; ++j) {
                float f = bf2f((unsigned short)ar[j]);
                f = fmaxf(fmaf(f, aS, bS), 0.f);
                af[j] = (short)f2bf(f);
            }
#pragma unroll
            for (int t = 0; t < Tk; ++t)
                acc[g][t] = __builtin_amdgcn_mfma_f32_16x16x32_bf16(B[t], af, acc[g][t], 0, 0, 0);
        }
    }

    float ls = 0.f, lq = 0.f;
#pragma unroll
    for (int g = 0; g < G; ++g) {
        size_t zrow = ((size_t)(bc * freqs + fg * G + g) * SS + wv * 16 + m) * MT;
#pragma unroll
        for (int t = 0; t < Tk; ++t) {
            ushort4 u;
            u.x = f2bf(acc[g][t][0]);
            u.y = f2bf(acc[g][t][1]);
            u.z = f2bf(acc[g][t][2]);
            u.w = f2bf(acc[g][t][3]);
            *(ushort4*)&zz[zrow + t * 16 + q * 4] = u;
#pragma unroll
            for (int reg = 0; reg < 4; ++reg) {
                float v = acc[g][t][reg];
                ls += v; lq += v * v;
            }
        }
    }
#pragma unroll
    for (int o = 32; o > 0; o >>= 1) {
        ls += __shfl_down(ls, o, 64);
        lq += __shfl_down(lq, o, 64);
    }
    if (lane == 0) { ssum[wv] = ls; ssq[wv] = lq; }
    __syncthreads();
    if (tid == 0) {
        int rep = sub & 63;
        atomicAdd(&statR2[rep * 32 + kidx * 2 + c],      ssum[0] + ssum[1] + ssum[2] + ssum[3]);
        atomicAdd(&statR2[rep * 32 + 16 + kidx * 2 + c], ssq[0] + ssq[1] + ssq[2] + ssq[3]);
    }
}

// ---------------- stage 2 fused: all 5 buckets in one launch ----------------
//   [   0, 256) -> bucket3 Tk=4 G=4  (256 blocks)
//   [ 256, 512) -> bucket2 Tk=3 G=4  (256 blocks)
//   [ 512,1024) -> bucket4 Tk=8 G=2  (512 blocks)
//   [1024,1152) -> bucket1 Tk=2 G=4  (128 blocks)
//   [1152,1280) -> bucket0 Tk=1 G=4  (128 blocks)
__global__ __launch_bounds__(256) void k_deinterp_all(
    const unsigned short* __restrict__ y, const unsigned short* __restrict__ w2,
    const float* __restrict__ da, const float* __restrict__ db,
    unsigned short* __restrict__ z, float* __restrict__ statR2)
{
    __shared__ float ssum[4], ssq[4];
    const int b = blockIdx.x;
    if (b < 256) {
        deinterp_body<4, 4>(b,        y, w2 + 12288, da, db, z + 4718592, statR2, 128, 64, 3, ssum, ssq);
    } else if (b < 512) {
        deinterp_body<3, 4>(b - 256,  y, w2 + 6144,  da, db, z + 1572864, statR2,  64, 64, 2, ssum, ssq);
    } else if (b < 1024) {
        deinterp_body<8, 2>(b - 512,  y, w2 + 20480, da, db, z + 8912896, statR2, 192, 64, 4, ssum, ssq);
    } else if (b < 1152) {
        deinterp_body<2, 4>(b - 1024, y, w2 + 2048,  da, db, z + 524288,  statR2,  32, 32, 1, ssum, ssq);
    } else {
        deinterp_body<1, 4>(b - 1152, y, w2 + 0,     da, db, z + 0,       statR2,   0, 32, 0, ssum, ssq);
    }
}

// ---------------- stage 2b: fold replicas -> per-(bucket,c) BN coefficients ----------------
__global__ void k_di_ab(const float* __restrict__ statR2,
                        const float* __restrict__ g0, const float* __restrict__ g1,
                        const float* __restrict__ g2, const float* __restrict__ g3,
                        const float* __restrict__ g4,
                        const float* __restrict__ b0, const float* __restrict__ b1,
                        const float* __restrict__ b2, const float* __restrict__ b3,
                        const float* __restrict__ b4,
                        float* __restrict__ ab)
{
    int tid = threadIdx.x;
    int i = tid >> 4, j = tid & 15;           // 160 threads: 16 lanes per output
    if (i < 10) {
        float sm = 0.f, sq = 0.f;
        for (int rep = j; rep < 64; rep += 16) {
            sm += statR2[rep * 32 + i];
            sq += statR2[rep * 32 + 16 + i];
        }
#pragma unroll
        for (int o = 8; o > 0; o >>= 1) {
            sm += __shfl_down(sm, o, 16);
            sq += __shfl_down(sq, o, 16);
        }
        if (j == 0) {
            int kb = i >> 1, c = i & 1;
            const float Nv[5] = {262144.f, 524288.f, 1572864.f, 2097152.f, 4194304.f};
            const float* gp[5] = {g0, g1, g2, g3, g4};
            const float* bp[5] = {b0, b1, b2, b3, b4};
            float mean = sm / Nv[kb];
            float var  = sq / Nv[kb] - mean * mean;
            float a = gp[kb][c] * rsqrtf(var + EPSV);
            ab[i * 2]     = a;
            ab[i * 2 + 1] = bp[kb][c] - mean * a;
        }
    }
}

// ---------------- BN+ReLU epilogue: bf16 z -> fp32 out (8 elems / thread) ----------------
__global__ __launch_bounds__(256) void k_bn_out(
    const unsigned short* __restrict__ z, const float* __restrict__ ab,
    float* __restrict__ out)
{
    int i8 = blockIdx.x * 256 + threadIdx.x;
    if (i8 >= 2162688) return;
    int kb, off8, cs8;
    if (i8 < 65536)        { kb = 0; off8 = 0;       cs8 = 4096;  }
    else if (i8 < 196608)  { kb = 1; off8 = 65536;   cs8 = 8192;  }
    else if (i8 < 589824)  { kb = 2; off8 = 196608;  cs8 = 24576; }
    else if (i8 < 1114112) { kb = 3; off8 = 589824;  cs8 = 32768; }
    else                   { kb = 4; off8 = 1114112; cs8 = 65536; }
    int c = ((i8 - off8) / cs8) & 1;
    float a = ab[(kb * 2 + c) * 2], b = ab[(kb * 2 + c) * 2 + 1];
    const unsigned short* zp = z + (size_t)i8 * 8;
    ushort4 u0 = *(const ushort4*)zp;
    ushort4 u1 = *(const ushort4*)(zp + 4);
    float4 o0, o1;
    o0.x = fmaxf(fmaf(bf2f(u0.x), a, b), 0.f);
    o0.y = fmaxf(fmaf(bf2f(u0.y), a, b), 0.f);
    o0.z = fmaxf(fmaf(bf2f(u0.z), a, b), 0.f);
    o0.w = fmaxf(fmaf(bf2f(u0.w), a, b), 0.f);
    o1.x = fmaxf(fmaf(bf2f(u1.x), a, b), 0.f);
    o1.y = fmaxf(fmaf(bf2f(u1.y), a, b), 0.f);
    o1.z = fmaxf(fmaf(bf2f(u1.z), a, b), 0.f);
    o1.w = fmaxf(fmaf(bf2f(u1.w), a, b), 0.f);
    float* op = out + (size_t)i8 * 8;
    *(float4*)op       = o0;
    *(float4*)(op + 4) = o1;
}

// ---------------- launch ----------------
extern "C" void kernel_launch(void* const* d_in, const int* in_sizes, int n_in,
                              void* d_out, int out_size, void* d_ws, size_t ws_size,
                              hipStream_t stream)
{
    const float* x      = (const float*)d_in[0];
    const float* imean  = (const float*)d_in[1];
    const float* iscale = (const float*)d_in[2];
    const float* Wdeo   = (const float*)d_in[3];
    const float* gdeo   = (const float*)d_in[4];
    const float* bdeo   = (const float*)d_in[5];
    const float* Wdi[5] = {(const float*)d_in[7],  (const float*)d_in[10],
                           (const float*)d_in[13], (const float*)d_in[16],
                           (const float*)d_in[19]};
    const float* gdi[5] = {(const float*)d_in[8],  (const float*)d_in[11],
                           (const float*)d_in[14], (const float*)d_in[17],
                           (const float*)d_in[20]};
    const float* bdi[5] = {(const float*)d_in[9],  (const float*)d_in[12],
                           (const float*)d_in[15], (const float*)d_in[18],
                           (const float*)d_in[21]};
    float* out = (float*)d_out;
    float* ws  = (float*)d_ws;

    unsigned short* y  = (unsigned short*)(ws + YOFF);
    unsigned short* z  = (unsigned short*)(ws + ZOFF);
    unsigned short* w1 = (unsigned short*)(ws + W1OFF);
    unsigned short* w2 = (unsigned short*)(ws + W2OFF);
    float* st     = ws + STATF;
    float* da     = st + OFF_DA;
    float* db     = st + OFF_DB;
    float* diab   = st + OFF_DIAB;
    float* statR  = st + OFF_STATR;
    float* statR2 = st + OFF_STATR2;

    k_prep<<<348, 256, 0, stream>>>(Wdeo, Wdi[0], Wdi[1], Wdi[2], Wdi[3], Wdi[4],
                                    w1, w2, st);

    k_deoverlap<<<BB * CC * FF, 256, 0, stream>>>(x, imean, iscale, w1, y, statR);
    k_deo_ab<<<1, 512, 0, stream>>>(statR, gdeo, bdeo, da, db);

    k_deinterp_all<<<1280, 256, 0, stream>>>(y, w2, da, db, z, statR2);

    k_di_ab<<<1, 160, 0, stream>>>(statR2,
                                   gdi[0], gdi[1], gdi[2], gdi[3], gdi[4],
                                   bdi[0], bdi[1], bdi[2], bdi[3], bdi[4], diab);

    k_bn_out<<<8448, 256, 0, stream>>>(z, diab, out);
}

// Round 4
// 239.822 us; speedup vs baseline: 1.0916x; 1.0108x over previous
//
#include <hip/hip_runtime.h>
#include <cstddef>

// ---------------- problem constants ----------------
#define BB   8
#define CC   2
#define FF   256
#define TT   4160      // ncoefs
#define SS   64        // nb_slices
#define NW   128       // NWIN
#define KW   256       // 2*NWIN
#define EPSV 1e-5f
#define RPB  4         // rows per block in k_deoverlap

typedef __attribute__((ext_vector_type(8))) short bf16x8;   // 8 bf16 = 4 VGPRs
typedef __attribute__((ext_vector_type(4))) float f32x4;

// ---------------- ws layout (float offsets) ----------------
#define YOFF    0
#define ZOFF    16777216
#define W1OFF   25427968
#define W2OFF   25444352
#define STATF   25462784
#define OFF_DA     256
#define OFF_DB     384
#define OFF_DIAB   544
#define OFF_STATR  1024    // 64 reps x [sum(128) | sq(128)]  (stage-1)
#define OFF_STATR2 17408   // 64 reps x [sum(16)  | sq(16) ]  (stage-2)
#define NZERO   19456

// manual bf16 conversions (RNE)
__device__ __forceinline__ unsigned short f2bf(float f) {
    unsigned int u = __builtin_bit_cast(unsigned int, f);
    u = (u + 0x7FFFu + ((u >> 16) & 1u)) >> 16;
    return (unsigned short)u;
}
__device__ __forceinline__ float bf2f(unsigned short h) {
    return __builtin_bit_cast(float, (unsigned int)h << 16);
}

// ---------------- prep: zero stats + frag-ordered bf16 W_deo (w1) + W_di (w2) ----------------
__global__ __launch_bounds__(256) void k_prep(
    const float* __restrict__ Wdeo,
    const float* __restrict__ Wdi0, const float* __restrict__ Wdi1,
    const float* __restrict__ Wdi2, const float* __restrict__ Wdi3,
    const float* __restrict__ Wdi4,
    unsigned short* __restrict__ w1, unsigned short* __restrict__ w2,
    float* __restrict__ statz)
{
    int gid = blockIdx.x * 256 + threadIdx.x;
    if (gid < NZERO) statz[gid] = 0.f;
    int id = gid - NZERO;
    if (id >= 0 && id < 32768) {
        int j = id & 7, lane = (id >> 3) & 63, nt = (id >> 9) & 7, ks = id >> 12;
        int n = nt * 16 + (lane & 15);
        int k = ks * 32 + ((lane >> 4) << 3) + j;
        w1[id] = f2bf(Wdeo[n * KW + k]);
    }
    id -= 32768;
    if (id >= 0 && id < 36864) {
        const float* W; int base, Tk;
        if (id < 2048)       { W = Wdi0; base = 0;     Tk = 1; }
        else if (id < 6144)  { W = Wdi1; base = 2048;  Tk = 2; }
        else if (id < 12288) { W = Wdi2; base = 6144;  Tk = 3; }
        else if (id < 20480) { W = Wdi3; base = 12288; Tk = 4; }
        else                 { W = Wdi4; base = 20480; Tk = 8; }
        int e = id - base;
        int j = e & 7, lane = (e >> 3) & 63, rest = e >> 9;
        int t = rest % Tk, ks = rest / Tk;
        int n = t * 16 + (lane & 15);
        int k = ks * 32 + ((lane >> 4) << 3) + j;
        w2[id] = f2bf(W[n * NW + k]);
    }
}

// ---------------- stage-1 helpers: split staging (load early / write late) ----------------
__device__ __forceinline__ void deo_load_row(const float* __restrict__ xr, int tid,
                                             float2* xv)
{
#pragma unroll
    for (int k = 0; k < 9; ++k) {
        int p2 = tid + k * 256;
        int t = p2 * 2 - 64;
        float2 v; v.x = 0.f; v.y = 0.f;
        if (p2 < 2144 && t >= 0 && t + 1 < TT)
            v = *(const float2*)&xr[t];
        xv[k] = v;
    }
}
__device__ __forceinline__ void deo_write_row(unsigned short* __restrict__ xsb, int tid,
                                              const float2* xv, float mval, float sval)
{
#pragma unroll
    for (int k = 0; k < 9; ++k) {
        int p2 = tid + k * 256;
        if (p2 < 2144) {
            int i = p2 * 2;
            int t = i - 64;
            float v0 = (xv[k].x + mval) * sval;
            float v1 = (xv[k].y + mval) * sval;
            if (t < 0 || t + 1 >= TT) { v0 = 0.f; v1 = 0.f; }  // zero-pad semantics
            int phys = i ^ (((i >> 6) & 7) << 3);
            unsigned int pk = (unsigned int)f2bf(v0) | ((unsigned int)f2bf(v1) << 16);
            *(unsigned int*)&xsb[phys] = pk;
        }
    }
}

// ---------------- stage 1: normalize + deoverlap MFMA + stats (RPB rows / block) ----------------
// Software-pipelined: stage row r+1 (global->regs before MFMA, regs->LDS after),
// double-buffered LDS, one barrier per row. Operand-swapped MFMA as in r2.
__global__ __launch_bounds__(256) void k_deoverlap(
    const float* __restrict__ x, const float* __restrict__ imean,
    const float* __restrict__ iscale, const unsigned short* __restrict__ w1,
    unsigned short* __restrict__ y, float* __restrict__ statR)
{
    __shared__ __align__(16) unsigned short xs[2][4288];
    __shared__ float psA[4][64], pqA[4][64];
    const int tid = threadIdx.x;
    const int r0  = blockIdx.x * RPB;
    const int c   = (r0 >> 8) & 1;
    const int lane = tid & 63, wv = tid >> 6;
    const int q = lane >> 4, m = lane & 15;

    float statS[4] = {0.f, 0.f, 0.f, 0.f};
    float statQ[4] = {0.f, 0.f, 0.f, 0.f};

    // prologue: stage row 0 into buffer 0
    float2 xv[9];
    deo_load_row(x + (size_t)r0 * TT, tid, xv);
    deo_write_row(xs[0], tid, xv, imean[r0 & 255], iscale[r0 & 255]);
    __syncthreads();

#pragma unroll
    for (int rr = 0; rr < RPB; ++rr) {
        const int r = r0 + rr;
        // issue next-row global loads early (complete under this row's MFMA phase)
        float mnext = 0.f, snext = 0.f;
        if (rr < RPB - 1) {
            deo_load_row(x + (size_t)(r + 1) * TT, tid, xv);
            mnext = imean[(r0 & 255) + rr + 1];
            snext = iscale[(r0 & 255) + rr + 1];
        }

        // MFMA phase on current buffer
        const unsigned short* xsb = xs[rr & 1];
        f32x4 acc[4][2] = {};   // [stile][ntile]; D reg dim = n (contiguous in y)
        bf16x8 Bc0 = *(const bf16x8*)(w1 + ((size_t)((2 * wv + 0) * 64 + lane) << 3));
        bf16x8 Bc1 = *(const bf16x8*)(w1 + ((size_t)((2 * wv + 1) * 64 + lane) << 3));
#pragma unroll
        for (int ks = 0; ks < 8; ++ks) {
            bf16x8 Bn0, Bn1;
            if (ks < 7) {
                Bn0 = *(const bf16x8*)(w1 + ((size_t)(((ks + 1) * 8 + 2 * wv + 0) * 64 + lane) << 3));
                Bn1 = *(const bf16x8*)(w1 + ((size_t)(((ks + 1) * 8 + 2 * wv + 1) * 64 + lane) << 3));
            }
            const int k0 = ks * 32;
#pragma unroll
            for (int st = 0; st < 4; ++st) {
                int idx  = (st * 16 + m) * 64 + k0 + q * 8;
                int phys = idx ^ (((idx >> 6) & 7) << 3);
                bf16x8 A = *(const bf16x8*)&xsb[phys];
                acc[st][0] = __builtin_amdgcn_mfma_f32_16x16x32_bf16(Bc0, A, acc[st][0], 0, 0, 0);
                acc[st][1] = __builtin_amdgcn_mfma_f32_16x16x32_bf16(Bc1, A, acc[st][1], 0, 0, 0);
            }
            Bc0 = Bn0; Bc1 = Bn1;
        }

        // epilogue: y stores (8B vector) + stats accumulation in registers
#pragma unroll
        for (int st = 0; st < 4; ++st)
#pragma unroll
            for (int t = 0; t < 2; ++t) {
                ushort4 u;
                u.x = f2bf(acc[st][t][0]);
                u.y = f2bf(acc[st][t][1]);
                u.z = f2bf(acc[st][t][2]);
                u.w = f2bf(acc[st][t][3]);
                *(ushort4*)&y[(size_t)r * 8192 + (st * 16 + m) * NW + (2 * wv + t) * 16 + q * 4] = u;
#pragma unroll
                for (int reg = 0; reg < 4; ++reg) {
                    float v = acc[st][t][reg];
                    statS[st] += v; statQ[st] += v * v;
                }
            }

        // write next row into the other buffer; one barrier per row
        if (rr < RPB - 1) {
            deo_write_row(xs[(rr + 1) & 1], tid, xv, mnext, snext);
            __syncthreads();
        }
    }

    // block-level stats: shfl over q-groups -> LDS over waves -> replicated atomics
#pragma unroll
    for (int st = 0; st < 4; ++st) {
        float ps = statS[st], pq = statQ[st];
        ps += __shfl_xor(ps, 16, 64);  pq += __shfl_xor(pq, 16, 64);
        ps += __shfl_xor(ps, 32, 64);  pq += __shfl_xor(pq, 32, 64);
        if (q == 0) { psA[wv][st * 16 + m] = ps; pqA[wv][st * 16 + m] = pq; }
    }
    __syncthreads();
    if (tid < 128) {
        int s = tid & 63, which = tid >> 6;
        float v = which ? (pqA[0][s] + pqA[1][s] + pqA[2][s] + pqA[3][s])
                        : (psA[0][s] + psA[1][s] + psA[2][s] + psA[3][s]);
        int rep = blockIdx.x & 63;
        atomicAdd(&statR[rep * 256 + which * 128 + c * SS + s], v);
    }
}

// ---------------- stage 1b: fold replicas -> per-(c,s) BN coefficients ----------------
__global__ void k_deo_ab(const float* __restrict__ statR,
                         const float* __restrict__ g, const float* __restrict__ be,
                         float* __restrict__ da, float* __restrict__ db)
{
    __shared__ float red[4][256];
    int tid = threadIdx.x;
    int i = tid & 127, h = tid >> 7;          // 512 threads: 4 rep-chunks
    float sm = 0.f, sq = 0.f;
    for (int rep = h; rep < 64; rep += 4) {
        sm += statR[rep * 256 + i];
        sq += statR[rep * 256 + 128 + i];
    }
    red[h][i] = sm; red[h][128 + i] = sq;
    __syncthreads();
    if (h == 0) {
        sm = red[0][i] + red[1][i] + red[2][i] + red[3][i];
        sq = red[0][128 + i] + red[1][128 + i] + red[2][128 + i] + red[3][128 + i];
        int c = i >> 6;
        const float N = (float)(BB * FF * NW);
        float mean = sm / N;
        float var  = sq / N - mean * mean;
        float a = g[c] * rsqrtf(var + EPSV);
        da[i] = a;
        db[i] = be[c] - mean * a;
    }
}

// ---------------- stage 2 body: fused BN+ReLU + GEMM for one bucket sub-block ----------------
// Operand-swapped MFMA: D reg dim = m-cols of z (contiguous), cols = s.
// (Byte-identical to the round-2 passing version — no inline asm.)
template <int Tk, int G>
__device__ __forceinline__ void deinterp_body(
    int sub,
    const unsigned short* __restrict__ y, const unsigned short* __restrict__ wb,
    const float* __restrict__ da, const float* __restrict__ db,
    unsigned short* __restrict__ zz, float* __restrict__ statR2,
    int p, int freqs, int kidx, float* ssum, float* ssq)
{
    constexpr int MT = Tk * 16;
    const int tid = threadIdx.x, lane = tid & 63, wv = tid >> 6;
    const int q = lane >> 4, m = lane & 15;
    const int bc = sub & 15;
    const int fg = sub >> 4;
    const int c  = bc & 1;
    const int s  = wv * 16 + m;
    const float aS = da[c * SS + s], bS = db[c * SS + s];

    f32x4 acc[G][Tk] = {};
    const unsigned short* ybase = y + ((size_t)(bc * FF + p + fg * G) * SS) * NW;

#pragma unroll
    for (int ks = 0; ks < 4; ++ks) {
        bf16x8 B[Tk];
#pragma unroll
        for (int t = 0; t < Tk; ++t)
            B[t] = *(const bf16x8*)(wb + ((size_t)((ks * Tk + t) * 64 + lane) << 3));
#pragma unroll
        for (int g = 0; g < G; ++g) {
            bf16x8 ar = *(const bf16x8*)(ybase + ((size_t)g * SS + s) * NW + ks * 32 + q * 8);
            bf16x8 af;
#pragma unroll
            for (int j = 0; j < 8; ++j) {
                float f = bf2f((unsigned short)ar[j]);
                f = fmaxf(fmaf(f, aS, bS), 0.f);
                af[j] = (short)f2bf(f);
            }
#pragma unroll
            for (int t = 0; t < Tk; ++t)
                acc[g][t] = __builtin_amdgcn_mfma_f32_16x16x32_bf16(B[t], af, acc[g][t], 0, 0, 0);
        }
    }

    float ls = 0.f, lq = 0.f;
#pragma unroll
    for (int g = 0; g < G; ++g) {
        size_t zrow = ((size_t)(bc * freqs + fg * G + g) * SS + wv * 16 + m) * MT;
#pragma unroll
        for (int t = 0; t < Tk; ++t) {
            ushort4 u;
            u.x = f2bf(acc[g][t][0]);
            u.y = f2bf(acc[g][t][1]);
            u.z = f2bf(acc[g][t][2]);
            u.w = f2bf(acc[g][t][3]);
            *(ushort4*)&zz[zrow + t * 16 + q * 4] = u;
#pragma unroll
            for (int reg = 0; reg < 4; ++reg) {
                float v = acc[g][t][reg];
                ls += v; lq += v * v;
            }
        }
    }
#pragma unroll
    for (int o = 32; o > 0; o >>= 1) {
        ls += __shfl_down(ls, o, 64);
        lq += __shfl_down(lq, o, 64);
    }
    if (lane == 0) { ssum[wv] = ls; ssq[wv] = lq; }
    __syncthreads();
    if (tid == 0) {
        int rep = sub & 63;
        atomicAdd(&statR2[rep * 32 + kidx * 2 + c],      ssum[0] + ssum[1] + ssum[2] + ssum[3]);
        atomicAdd(&statR2[rep * 32 + 16 + kidx * 2 + c], ssq[0] + ssq[1] + ssq[2] + ssq[3]);
    }
}

// ---------------- stage 2 fused: all 5 buckets in one launch ----------------
//   [   0, 256) -> bucket3 Tk=4 G=4  (256 blocks)
//   [ 256, 512) -> bucket2 Tk=3 G=4  (256 blocks)
//   [ 512,1024) -> bucket4 Tk=8 G=2  (512 blocks)
//   [1024,1152) -> bucket1 Tk=2 G=4  (128 blocks)
//   [1152,1280) -> bucket0 Tk=1 G=4  (128 blocks)
__global__ __launch_bounds__(256) void k_deinterp_all(
    const unsigned short* __restrict__ y, const unsigned short* __restrict__ w2,
    const float* __restrict__ da, const float* __restrict__ db,
    unsigned short* __restrict__ z, float* __restrict__ statR2)
{
    __shared__ float ssum[4], ssq[4];
    const int b = blockIdx.x;
    if (b < 256) {
        deinterp_body<4, 4>(b,        y, w2 + 12288, da, db, z + 4718592, statR2, 128, 64, 3, ssum, ssq);
    } else if (b < 512) {
        deinterp_body<3, 4>(b - 256,  y, w2 + 6144,  da, db, z + 1572864, statR2,  64, 64, 2, ssum, ssq);
    } else if (b < 1024) {
        deinterp_body<8, 2>(b - 512,  y, w2 + 20480, da, db, z + 8912896, statR2, 192, 64, 4, ssum, ssq);
    } else if (b < 1152) {
        deinterp_body<2, 4>(b - 1024, y, w2 + 2048,  da, db, z + 524288,  statR2,  32, 32, 1, ssum, ssq);
    } else {
        deinterp_body<1, 4>(b - 1152, y, w2 + 0,     da, db, z + 0,       statR2,   0, 32, 0, ssum, ssq);
    }
}

// ---------------- stage 2b: fold replicas -> per-(bucket,c) BN coefficients ----------------
__global__ void k_di_ab(const float* __restrict__ statR2,
                        const float* __restrict__ g0, const float* __restrict__ g1,
                        const float* __restrict__ g2, const float* __restrict__ g3,
                        const float* __restrict__ g4,
                        const float* __restrict__ b0, const float* __restrict__ b1,
                        const float* __restrict__ b2, const float* __restrict__ b3,
                        const float* __restrict__ b4,
                        float* __restrict__ ab)
{
    int tid = threadIdx.x;
    int i = tid >> 4, j = tid & 15;           // 160 threads: 16 lanes per output
    if (i < 10) {
        float sm = 0.f, sq = 0.f;
        for (int rep = j; rep < 64; rep += 16) {
            sm += statR2[rep * 32 + i];
            sq += statR2[rep * 32 + 16 + i];
        }
#pragma unroll
        for (int o = 8; o > 0; o >>= 1) {
            sm += __shfl_down(sm, o, 16);
            sq += __shfl_down(sq, o, 16);
        }
        if (j == 0) {
            int kb = i >> 1, c = i & 1;
            const float Nv[5] = {262144.f, 524288.f, 1572864.f, 2097152.f, 4194304.f};
            const float* gp[5] = {g0, g1, g2, g3, g4};
            const float* bp[5] = {b0, b1, b2, b3, b4};
            float mean = sm / Nv[kb];
            float var  = sq / Nv[kb] - mean * mean;
            float a = gp[kb][c] * rsqrtf(var + EPSV);
            ab[i * 2]     = a;
            ab[i * 2 + 1] = bp[kb][c] - mean * a;
        }
    }
}

// ---------------- BN+ReLU epilogue: bf16 z -> fp32 out (8 elems / thread) ----------------
__global__ __launch_bounds__(256) void k_bn_out(
    const unsigned short* __restrict__ z, const float* __restrict__ ab,
    float* __restrict__ out)
{
    int i8 = blockIdx.x * 256 + threadIdx.x;
    if (i8 >= 2162688) return;
    int kb, off8, cs8;
    if (i8 < 65536)        { kb = 0; off8 = 0;       cs8 = 4096;  }
    else if (i8 < 196608)  { kb = 1; off8 = 65536;   cs8 = 8192;  }
    else if (i8 < 589824)  { kb = 2; off8 = 196608;  cs8 = 24576; }
    else if (i8 < 1114112) { kb = 3; off8 = 589824;  cs8 = 32768; }
    else                   { kb = 4; off8 = 1114112; cs8 = 65536; }
    int c = ((i8 - off8) / cs8) & 1;
    float a = ab[(kb * 2 + c) * 2], b = ab[(kb * 2 + c) * 2 + 1];
    const unsigned short* zp = z + (size_t)i8 * 8;
    ushort4 u0 = *(const ushort4*)zp;
    ushort4 u1 = *(const ushort4*)(zp + 4);
    float4 o0, o1;
    o0.x = fmaxf(fmaf(bf2f(u0.x), a, b), 0.f);
    o0.y = fmaxf(fmaf(bf2f(u0.y), a, b), 0.f);
    o0.z = fmaxf(fmaf(bf2f(u0.z), a, b), 0.f);
    o0.w = fmaxf(fmaf(bf2f(u0.w), a, b), 0.f);
    o1.x = fmaxf(fmaf(bf2f(u1.x), a, b), 0.f);
    o1.y = fmaxf(fmaf(bf2f(u1.y), a, b), 0.f);
    o1.z = fmaxf(fmaf(bf2f(u1.z), a, b), 0.f);
    o1.w = fmaxf(fmaf(bf2f(u1.w), a, b), 0.f);
    float* op = out + (size_t)i8 * 8;
    *(float4*)op       = o0;
    *(float4*)(op + 4) = o1;
}

// ---------------- launch ----------------
extern "C" void kernel_launch(void* const* d_in, const int* in_sizes, int n_in,
                              void* d_out, int out_size, void* d_ws, size_t ws_size,
                              hipStream_t stream)
{
    const float* x      = (const float*)d_in[0];
    const float* imean  = (const float*)d_in[1];
    const float* iscale = (const float*)d_in[2];
    const float* Wdeo   = (const float*)d_in[3];
    const float* gdeo   = (const float*)d_in[4];
    const float* bdeo   = (const float*)d_in[5];
    const float* Wdi[5] = {(const float*)d_in[7],  (const float*)d_in[10],
                           (const float*)d_in[13], (const float*)d_in[16],
                           (const float*)d_in[19]};
    const float* gdi[5] = {(const float*)d_in[8],  (const float*)d_in[11],
                           (const float*)d_in[14], (const float*)d_in[17],
                           (const float*)d_in[20]};
    const float* bdi[5] = {(const float*)d_in[9],  (const float*)d_in[12],
                           (const float*)d_in[15], (const float*)d_in[18],
                           (const float*)d_in[21]};
    float* out = (float*)d_out;
    float* ws  = (float*)d_ws;

    unsigned short* y  = (unsigned short*)(ws + YOFF);
    unsigned short* z  = (unsigned short*)(ws + ZOFF);
    unsigned short* w1 = (unsigned short*)(ws + W1OFF);
    unsigned short* w2 = (unsigned short*)(ws + W2OFF);
    float* st     = ws + STATF;
    float* da     = st + OFF_DA;
    float* db     = st + OFF_DB;
    float* diab   = st + OFF_DIAB;
    float* statR  = st + OFF_STATR;
    float* statR2 = st + OFF_STATR2;

    k_prep<<<348, 256, 0, stream>>>(Wdeo, Wdi[0], Wdi[1], Wdi[2], Wdi[3], Wdi[4],
                                    w1, w2, st);

    k_deoverlap<<<(BB * CC * FF) / RPB, 256, 0, stream>>>(x, imean, iscale, w1, y, statR);
    k_deo_ab<<<1, 512, 0, stream>>>(statR, gdeo, bdeo, da, db);

    k_deinterp_all<<<1280, 256, 0, stream>>>(y, w2, da, db, z, statR2);

    k_di_ab<<<1, 160, 0, stream>>>(statR2,
                                   gdi[0], gdi[1], gdi[2], gdi[3], gdi[4],
                                   bdi[0], bdi[1], bdi[2], bdi[3], bdi[4], diab);

    k_bn_out<<<8448, 256, 0, stream>>>(z, diab, out);
}